// Round 5
// baseline (16679.503 us; speedup 1.0000x reference)
//
#include <hip/hip_runtime.h>
#include <stdint.h>

#define TT 2048
#define BB 8
#define II 512
#define HH 512
#define GG 16           // workgroups per direction
#define HS 32           // hidden units per WG
#define NT 512          // threads per WG (8 waves)
#define SLOT 4096       // elems per h-history slot: 16 wg * 8 b * 32 u

typedef __attribute__((ext_vector_type(8))) short short8;
typedef __attribute__((ext_vector_type(4))) float float4v;
typedef unsigned long long ull;

__device__ __forceinline__ unsigned short f2bf(float f) {
  unsigned u = __builtin_bit_cast(unsigned, f);
  u = u + 0x7FFFu + ((u >> 16) & 1u);   // RNE
  return (unsigned short)(u >> 16);
}

__device__ __forceinline__ float fsigmoid(float x) {
  return __fdividef(1.0f, 1.0f + __expf(-x));
}
__device__ __forceinline__ float ftanh(float x) {
  float e = __expf(-2.0f * fabsf(x));   // in (0,1], never overflows
  float r = __fdividef(1.0f - e, 1.0f + e);
  return x < 0.0f ? -r : r;
}

// input[b][t][k] fp32  ->  xbf[t][b][k] bf16
__global__ void xprep_kernel(const float* __restrict__ x,
                             unsigned short* __restrict__ xbf) {
  int idx = blockIdx.x * 256 + threadIdx.x;
  int k8 = idx & 63;
  int bt = idx >> 6;
  int t  = bt & (TT - 1);
  int b  = bt >> 11;
  const float* src = x + ((size_t)b * TT + t) * II + (size_t)k8 * 8;
  float4v v0 = *(const float4v*)src;
  float4v v1 = *(const float4v*)(src + 4);
  short8 o;
  o[0] = (short)f2bf(v0[0]); o[1] = (short)f2bf(v0[1]);
  o[2] = (short)f2bf(v0[2]); o[3] = (short)f2bf(v0[3]);
  o[4] = (short)f2bf(v1[0]); o[5] = (short)f2bf(v1[1]);
  o[6] = (short)f2bf(v1[2]); o[7] = (short)f2bf(v1[3]);
  *(short8*)(xbf + ((size_t)t * BB + b) * II + (size_t)k8 * 8) = o;
}

// NOTE: no min-waves arg — __launch_bounds__(512,2) capped VGPRs at 128,
// which is exactly the size of a_x[]+a_h[] alone -> per-step spill reloads.
__global__ __launch_bounds__(NT) void lstm_kernel(
    const float* __restrict__ Wih_f, const float* __restrict__ Whh_f,
    const float* __restrict__ bih_f, const float* __restrict__ bhh_f,
    const float* __restrict__ Wih_b, const float* __restrict__ Whh_b,
    const float* __restrict__ bih_b, const float* __restrict__ bhh_b,
    const unsigned short* __restrict__ xbf,
    unsigned short* __restrict__ h_hist,
    int* __restrict__ flags,
    float* __restrict__ out)
{
  const int dir  = blockIdx.x >> 4;
  const int wg   = blockIdx.x & 15;
  const int tid  = threadIdx.x;
  const int wave = tid >> 6;
  const int lane = tid & 63;
  const int m    = lane & 15;         // B-col (batch) / A-row within tile
  const int q    = lane >> 4;         // quad
  const int bsafe = m & 7;            // clamp batch index (cols 8-15 unused)

  const int gate = wave & 3;          // 0=i 1=f 2=g 3=o
  const int rh   = wave >> 2;         // row-half within 32-unit slice

  const float* __restrict__ Wih = dir ? Wih_b : Wih_f;
  const float* __restrict__ Whh = dir ? Whh_b : Whh_f;
  const float* __restrict__ bih = dir ? bih_b : bih_f;
  const float* __restrict__ bhh = dir ? bhh_b : bhh_f;

  const int j0   = wg * HS;                      // hidden slice [j0, j0+32)
  const int grow = gate * HH + j0 + rh * 16 + m; // gate row (A[m][k])

  // ---- persistent weight A-fragments (A[m][k=q*8+j]) ----
  short8 a_x[16], a_h[16];
#pragma unroll
  for (int kf = 0; kf < 16; ++kf) {
    const float* p1 = Wih + (size_t)grow * II + kf * 32 + q * 8;
    const float* p2 = Whh + (size_t)grow * HH + kf * 32 + q * 8;
    short8 A, Bv;
#pragma unroll
    for (int j = 0; j < 8; ++j) {
      A[j]  = (short)f2bf(p1[j]);
      Bv[j] = (short)f2bf(p2[j]);
    }
    a_x[kf] = A;
    a_h[kf] = Bv;
  }

  // ---- epilogue-persistent state (threads 0..255: cell (u, b)) ----
  float c_state = 0.0f;
  float bias_i = 0.f, bias_ff = 0.f, bias_g = 0.f, bias_o = 0.f;
  const int u  = tid & 31;
  const int b  = tid >> 5;            // valid when tid < 256
  if (tid < 256) {
    int j = j0 + u;
    bias_i  = bih[0 * HH + j] + bhh[0 * HH + j];
    bias_ff = bih[1 * HH + j] + bhh[1 * HH + j];
    bias_g  = bih[2 * HH + j] + bhh[2 * HH + j];
    bias_o  = bih[3 * HH + j] + bhh[3 * HH + j];
  }

  __shared__ float lds_g[4][32][9];                    // [gate][u][b], pad 9
  __shared__ __align__(8) unsigned short h_stage[8][32];  // [b][u]

  unsigned short* __restrict__ hh = h_hist + (size_t)dir * (TT + 1) * SLOT;
  int* __restrict__ flg = flags + dir * TT * GG;

  // ---- x-part for step 0 ----
  float4v acc[4];
#pragma unroll
  for (int i = 0; i < 4; ++i) acc[i] = (float4v){0.f, 0.f, 0.f, 0.f};
  {
    const int t0 = dir ? (TT - 1) : 0;
    const unsigned short* xrow = xbf + ((size_t)t0 * BB + bsafe) * II + q * 8;
#pragma unroll
    for (int kf = 0; kf < 16; ++kf) {
      short8 v = *(const short8*)(xrow + kf * 32);
      acc[kf & 3] = __builtin_amdgcn_mfma_f32_16x16x32_bf16(
          a_x[kf], v, acc[kf & 3], 0, 0, 0);
    }
  }

  int bail = 20000000;

#pragma unroll 1
  for (int s = 0; s < TT; ++s) {
    const int t = dir ? (TT - 1 - s) : s;

    // ---- wait for h(s-1): designated poller wave, others park at barrier ----
    if (s > 0) {
      if (wave == 7) {
        const int* fl = flg + (size_t)(s - 1) * GG;
        for (;;) {
          int v = (lane < GG)
                      ? __hip_atomic_load(&fl[lane], __ATOMIC_RELAXED,
                                          __HIP_MEMORY_SCOPE_AGENT)
                      : 1;
          if (__ballot(v == 0) == 0ull) break;
          if (--bail < 0) break;
        }
      }
      __syncthreads();
    }

    // ---- h contribution (agent-scope 8B loads from packed slot) ----
    // slot layout (shorts): idx = kf*256 + b*32 + off   (kf-block = 32 units)
    {
      const ull* hq = (const ull*)(hh + (size_t)s * SLOT);
      const int base = bsafe * 8 + q * 2;   // ull index within kf block of 64
      short8 bh[16];
#pragma unroll
      for (int kf = 0; kf < 16; ++kf) {
        ull u0 = __hip_atomic_load(&hq[kf * 64 + base + 0], __ATOMIC_RELAXED,
                                   __HIP_MEMORY_SCOPE_AGENT);
        ull u1 = __hip_atomic_load(&hq[kf * 64 + base + 1], __ATOMIC_RELAXED,
                                   __HIP_MEMORY_SCOPE_AGENT);
        ull two[2] = {u0, u1};
        bh[kf] = __builtin_bit_cast(short8, two);
      }
#pragma unroll
      for (int kf = 0; kf < 16; ++kf)
        acc[kf & 3] = __builtin_amdgcn_mfma_f32_16x16x32_bf16(
            a_h[kf], bh[kf], acc[kf & 3], 0, 0, 0);
    }

    // ---- gates to LDS (C/D layout: col=m=batch, row=q*4+r) ----
    if (m < 8) {
#pragma unroll
      for (int r = 0; r < 4; ++r) {
        float g = acc[0][r] + acc[1][r] + acc[2][r] + acc[3][r];
        lds_g[gate][rh * 16 + q * 4 + r][m] = g;
      }
    }
    __syncthreads();

    // ---- elementwise cell update; c persistent in registers ----
    if (tid < 256) {
      float gi = lds_g[0][u][b] + bias_i;
      float gf = lds_g[1][u][b] + bias_ff;
      float gg = lds_g[2][u][b] + bias_g;
      float go = lds_g[3][u][b] + bias_o;
      float si = fsigmoid(gi);
      float sf = fsigmoid(gf);
      float tg = ftanh(gg);
      float so = fsigmoid(go);
      c_state = sf * c_state + si * tg;
      float hv = so * ftanh(c_state);
      h_stage[b][u] = f2bf(hv);
      __builtin_nontemporal_store(
          hv, &out[((size_t)t * BB + b) * (2 * HH) + (size_t)dir * HH + j0 + u]);
    }
    __syncthreads();

    // ---- publish h(s) + flag (wave 0); others start x-part for s+1 ----
    if (s + 1 < TT) {
      if (tid < 64) {
        // WG wg owns kf-block wg: ull offset wg*64 .. wg*64+63
        ull v = ((const ull*)h_stage)[tid];
        ull* hw = (ull*)(hh + (size_t)(s + 1) * SLOT) + (size_t)wg * 64 + tid;
        __hip_atomic_store(hw, v, __ATOMIC_RELAXED, __HIP_MEMORY_SCOPE_AGENT);
        asm volatile("s_waitcnt vmcnt(0)" ::: "memory");
        if (tid == 0)
          __hip_atomic_store(&flg[(size_t)s * GG + wg], 1, __ATOMIC_RELAXED,
                             __HIP_MEMORY_SCOPE_AGENT);
      }

      // ---- x contribution for step s+1 (off the critical path) ----
#pragma unroll
      for (int i = 0; i < 4; ++i) acc[i] = (float4v){0.f, 0.f, 0.f, 0.f};
      const int tn = dir ? (TT - 2 - s) : (s + 1);
      const unsigned short* xrow = xbf + ((size_t)tn * BB + bsafe) * II + q * 8;
#pragma unroll
      for (int kf = 0; kf < 16; ++kf) {
        short8 v = *(const short8*)(xrow + kf * 32);
        acc[kf & 3] = __builtin_amdgcn_mfma_f32_16x16x32_bf16(
            a_x[kf], v, acc[kf & 3], 0, 0, 0);
      }
    }
  }
}

extern "C" void kernel_launch(void* const* d_in, const int* in_sizes, int n_in,
                              void* d_out, int out_size, void* d_ws, size_t ws_size,
                              hipStream_t stream) {
  (void)in_sizes; (void)n_in; (void)out_size; (void)ws_size;
  const float* input = (const float*)d_in[0];
  const float* Wih_f = (const float*)d_in[1];
  const float* Whh_f = (const float*)d_in[2];
  const float* bih_f = (const float*)d_in[3];
  const float* bhh_f = (const float*)d_in[4];
  const float* Wih_b = (const float*)d_in[5];
  const float* Whh_b = (const float*)d_in[6];
  const float* bih_b = (const float*)d_in[7];
  const float* bhh_b = (const float*)d_in[8];

  char* ws = (char*)d_ws;
  // [xbf 16,777,216 B][h_hist 2*(TT+1)*SLOT*2 = 33,562,624 B][flags 262,144 B]
  unsigned short* xbf    = (unsigned short*)(ws);
  unsigned short* h_hist = (unsigned short*)(ws + 16777216);
  int*            flags  = (int*)(ws + 16777216 + 33562624);

  hipMemsetAsync(flags, 0, 2 * TT * GG * sizeof(int), stream);
  hipMemsetAsync(h_hist, 0, SLOT * 2, stream);                                 // dir0 h(-1)
  hipMemsetAsync((char*)h_hist + (size_t)(TT + 1) * SLOT * 2, 0, SLOT * 2, stream); // dir1

  hipLaunchKernelGGL(xprep_kernel, dim3(4096), dim3(256), 0, stream, input, xbf);
  hipLaunchKernelGGL(lstm_kernel, dim3(32), dim3(NT), 0, stream,
                     Wih_f, Whh_f, bih_f, bhh_f, Wih_b, Whh_b, bih_b, bhh_b,
                     xbf, h_hist, flags, (float*)d_out);
}

// Round 6
// 15364.107 us; speedup vs baseline: 1.0856x; 1.0856x over previous
//
#include <hip/hip_runtime.h>
#include <stdint.h>

#define TT 2048
#define BB 8
#define II 512
#define HH 512
#define GG 32            // workgroups per direction
#define HS 16            // hidden units per WG
#define NT 256           // threads per WG (4 waves)
#define WSLOT 4096       // 4B words per h slot (b*512 + k)
#define USLOT 2048       // 8B ulls per h slot

typedef __attribute__((ext_vector_type(8))) short short8;
typedef __attribute__((ext_vector_type(4))) float float4v;
typedef __attribute__((ext_vector_type(4))) unsigned int uint4v;
typedef unsigned long long ull;

__device__ __forceinline__ unsigned short f2bf(float f) {
  unsigned u = __builtin_bit_cast(unsigned, f);
  u = u + 0x7FFFu + ((u >> 16) & 1u);   // RNE
  return (unsigned short)(u >> 16);
}

__device__ __forceinline__ float fsigmoid(float x) {
  return __fdividef(1.0f, 1.0f + __expf(-x));
}
__device__ __forceinline__ float ftanh(float x) {
  float e = __expf(-2.0f * fabsf(x));
  float r = __fdividef(1.0f - e, 1.0f + e);
  return x < 0.0f ? -r : r;
}

// input[b][t][k] fp32  ->  xbf[t][b][k] bf16
__global__ void xprep_kernel(const float* __restrict__ x,
                             unsigned short* __restrict__ xbf) {
  int idx = blockIdx.x * 256 + threadIdx.x;
  int k8 = idx & 63;
  int bt = idx >> 6;
  int t  = bt & (TT - 1);
  int b  = bt >> 11;
  const float* src = x + ((size_t)b * TT + t) * II + (size_t)k8 * 8;
  float4v v0 = *(const float4v*)src;
  float4v v1 = *(const float4v*)(src + 4);
  short8 o;
  o[0] = (short)f2bf(v0[0]); o[1] = (short)f2bf(v0[1]);
  o[2] = (short)f2bf(v0[2]); o[3] = (short)f2bf(v0[3]);
  o[4] = (short)f2bf(v1[0]); o[5] = (short)f2bf(v1[1]);
  o[6] = (short)f2bf(v1[2]); o[7] = (short)f2bf(v1[3]);
  *(short8*)(xbf + ((size_t)t * BB + b) * II + (size_t)k8 * 8) = o;
}

// seed slot 0 of both directions with h=0, marker bit set
__global__ void hinit_kernel(unsigned int* __restrict__ hw) {
  int idx = blockIdx.x * 256 + threadIdx.x;   // 8192 threads
  int d = idx >> 12;
  int w = idx & 4095;
  hw[(size_t)d * (TT + 1) * WSLOT + w] = 1u;
}

__global__ __launch_bounds__(NT, 1) void lstm_kernel(
    const float* __restrict__ Wih_f, const float* __restrict__ Whh_f,
    const float* __restrict__ bih_f, const float* __restrict__ bhh_f,
    const float* __restrict__ Wih_b, const float* __restrict__ Whh_b,
    const float* __restrict__ bih_b, const float* __restrict__ bhh_b,
    const unsigned short* __restrict__ xbf,
    unsigned int* __restrict__ hwords,
    float* __restrict__ out)
{
  const int dir  = blockIdx.x >> 5;
  const int wg   = blockIdx.x & 31;
  const int tid  = threadIdx.x;
  const int wave = tid >> 6;          // gate: 0=i 1=f 2=g 3=o
  const int lane = tid & 63;
  const int m    = lane & 15;         // B-col (batch) / A-row in tile
  const int q    = lane >> 4;         // quad
  const int b    = m & 7;             // batch (cols 8-15 duplicate / unused)
  const bool bval = (m < 8);

  const float* __restrict__ Wih = dir ? Wih_b : Wih_f;
  const float* __restrict__ Whh = dir ? Whh_b : Whh_f;
  const float* __restrict__ bih = dir ? bih_b : bih_f;
  const float* __restrict__ bhh = dir ? bhh_b : bhh_f;

  const int j0   = wg * HS;                 // hidden slice [j0, j0+16)
  const int grow = wave * HH + j0 + m;      // gate row (A[m][k])

  // ---- persistent weight A-fragments (A[m][k=kf*32+q*8+j]) ----
  short8 a_x[16], a_h[16];
#pragma unroll
  for (int kf = 0; kf < 16; ++kf) {
    const float* p1 = Wih + (size_t)grow * II + kf * 32 + q * 8;
    const float* p2 = Whh + (size_t)grow * HH + kf * 32 + q * 8;
    short8 A, Bv;
#pragma unroll
    for (int j = 0; j < 8; ++j) {
      A[j]  = (short)f2bf(p1[j]);
      Bv[j] = (short)f2bf(p2[j]);
    }
    a_x[kf] = A;
    a_h[kf] = Bv;
  }

  // ---- epilogue state (threads 0..127: cell (jj, bb)) ----
  float c_state = 0.0f;
  float bias_i = 0.f, bias_ff = 0.f, bias_g = 0.f, bias_o = 0.f;
  const int jj = tid & 15;
  const int bb = tid >> 4;
  if (tid < 128) {
    int j = j0 + jj;
    bias_i  = bih[0 * HH + j] + bhh[0 * HH + j];
    bias_ff = bih[1 * HH + j] + bhh[1 * HH + j];
    bias_g  = bih[2 * HH + j] + bhh[2 * HH + j];
    bias_o  = bih[3 * HH + j] + bhh[3 * HH + j];
  }

  __shared__ float lds_g[2][4][16][17];   // parity double-buffer

  unsigned int* __restrict__ hw = hwords + (size_t)dir * (TT + 1) * WSLOT;
  const ull* __restrict__ hu = (const ull*)hw;

  // ---- prefetch x-fragments for step 0 ----
  short8 bx[16];
  {
    const int t0 = dir ? (TT - 1) : 0;
    const unsigned short* xrow = xbf + ((size_t)t0 * BB + b) * II + q * 8;
#pragma unroll
    for (int kf = 0; kf < 16; ++kf) bx[kf] = *(const short8*)(xrow + kf * 32);
  }

  int bail = 1000000;

#pragma unroll 1
  for (int s = 0; s < TT; ++s) {
    const int t = dir ? (TT - 1 - s) : s;

    // ---- x contribution (bx prefetched last step) ----
    float4v acc[4];
#pragma unroll
    for (int i = 0; i < 4; ++i) acc[i] = (float4v){0.f, 0.f, 0.f, 0.f};
#pragma unroll
    for (int kf = 0; kf < 16; ++kf)
      acc[kf & 3] = __builtin_amdgcn_mfma_f32_16x16x32_bf16(
          a_x[kf], bx[kf], acc[kf & 3], 0, 0, 0);

    // ---- poll h(s-1): data IS the flag (marker bit0 per 4B word) ----
    // word layout: w[b*512 + k], k = kf*32 + q*8 + j
    ull w[64];
    {
      const ull* hp = hu + (size_t)s * USLOT + (size_t)b * 256 + q * 4;
      for (;;) {
        unsigned ok = 1u;
#pragma unroll
        for (int i = 0; i < 64; ++i) {
          ull v = 0x0000000100000001ull;
          if (bval)
            v = __hip_atomic_load(&hp[(i >> 2) * 16 + (i & 3)],
                                  __ATOMIC_RELAXED, __HIP_MEMORY_SCOPE_AGENT);
          w[i] = v;
          ok &= (unsigned)v & (unsigned)(v >> 32);
        }
        if (__ballot((ok & 1u) == 0u) == 0ull) break;
        if (--bail < 0) break;
      }
    }

    // ---- extract bf16 pairs + h-MFMA ----
#pragma unroll
    for (int kf = 0; kf < 16; ++kf) {
      uint4v f;
#pragma unroll
      for (int j = 0; j < 4; ++j) {
        ull v = w[kf * 4 + j];
        f[j] = __builtin_amdgcn_perm((unsigned)(v >> 32), (unsigned)v,
                                     0x07060302u);
      }
      acc[kf & 3] = __builtin_amdgcn_mfma_f32_16x16x32_bf16(
          a_h[kf], __builtin_bit_cast(short8, f), acc[kf & 3], 0, 0, 0);
    }

    // ---- gates to LDS (C/D layout: col=m, row=q*4+r), parity buffer ----
    const int p = s & 1;
#pragma unroll
    for (int r = 0; r < 4; ++r) {
      float g = acc[0][r] + acc[1][r] + acc[2][r] + acc[3][r];
      lds_g[p][wave][q * 4 + r][m] = g;
    }
    __syncthreads();   // the ONLY barrier per step

    // ---- cell update + publish (no ack, no fence: marker rides the word) ----
    if (tid < 128) {
      float gi = lds_g[p][0][jj][bb] + bias_i;
      float gf = lds_g[p][1][jj][bb] + bias_ff;
      float gg = lds_g[p][2][jj][bb] + bias_g;
      float go = lds_g[p][3][jj][bb] + bias_o;
      float si = fsigmoid(gi);
      float sf = fsigmoid(gf);
      float tg = ftanh(gg);
      float so = fsigmoid(go);
      c_state = sf * c_state + si * tg;
      float hv = so * ftanh(c_state);
      if (s + 1 < TT) {
        unsigned word = ((unsigned)f2bf(hv) << 16) | 1u;
        __hip_atomic_store(&hw[(size_t)(s + 1) * WSLOT + bb * 512 + j0 + jj],
                           word, __ATOMIC_RELAXED, __HIP_MEMORY_SCOPE_AGENT);
      }
      __builtin_nontemporal_store(
          hv, &out[((size_t)t * BB + bb) * (2 * HH) + (size_t)dir * HH + j0 + jj]);
    }

    // ---- prefetch x for step s+1 (hides HBM latency under next poll) ----
    if (s + 1 < TT) {
      const int tn = dir ? (TT - 2 - s) : (s + 1);
      const unsigned short* xrow = xbf + ((size_t)tn * BB + b) * II + q * 8;
#pragma unroll
      for (int kf = 0; kf < 16; ++kf) bx[kf] = *(const short8*)(xrow + kf * 32);
    }
  }
}

extern "C" void kernel_launch(void* const* d_in, const int* in_sizes, int n_in,
                              void* d_out, int out_size, void* d_ws, size_t ws_size,
                              hipStream_t stream) {
  (void)in_sizes; (void)n_in; (void)out_size; (void)ws_size;
  const float* input = (const float*)d_in[0];
  const float* Wih_f = (const float*)d_in[1];
  const float* Whh_f = (const float*)d_in[2];
  const float* bih_f = (const float*)d_in[3];
  const float* bhh_f = (const float*)d_in[4];
  const float* Wih_b = (const float*)d_in[5];
  const float* Whh_b = (const float*)d_in[6];
  const float* bih_b = (const float*)d_in[7];
  const float* bhh_b = (const float*)d_in[8];

  char* ws = (char*)d_ws;
  // [xbf 16,777,216 B][hwords 2*(TT+1)*4096*4 = 67,141,632 B] = 83.9 MB
  unsigned short* xbf    = (unsigned short*)(ws);
  unsigned int*   hwords = (unsigned int*)(ws + 16777216);

  hipLaunchKernelGGL(xprep_kernel, dim3(4096), dim3(256), 0, stream, input, xbf);
  hipLaunchKernelGGL(hinit_kernel, dim3(32), dim3(256), 0, stream, hwords);
  hipLaunchKernelGGL(lstm_kernel, dim3(64), dim3(NT), 0, stream,
                     Wih_f, Whh_f, bih_f, bhh_f, Wih_b, Whh_b, bih_b, bhh_b,
                     xbf, hwords, (float*)d_out);
}